// Round 1
// baseline (1081.609 us; speedup 1.0000x reference)
//
#include <hip/hip_runtime.h>

// BasisAttention: B=16,S=2048,D=1024,N=4096,K_TOP=64. fp32 in/out.
// Strategy: fp32-accurate GEMMs via 3-product bf16 split (hi/lo) MFMA.

namespace {

constexpr int D_DIM = 1024;
constexpr int NE    = 4096;
constexpr int BATCH = 16;
constexpr int SEQ   = 2048;
constexpr int MX    = BATCH * SEQ;   // 32768
constexpr int MCH   = 8192;          // m-chunk (4 chunks)
constexpr int KTOP  = 64;
constexpr int BK    = 32;

using f32x4  = __attribute__((ext_vector_type(4))) float;
using bf16x8 = __attribute__((ext_vector_type(8))) short;

__device__ inline unsigned encf(float f) {
  unsigned u = __float_as_uint(f);
  return (u & 0x80000000u) ? ~u : (u | 0x80000000u);
}
__device__ inline float decf(unsigned e) {
  unsigned u = (e & 0x80000000u) ? (e ^ 0x80000000u) : ~e;
  return __uint_as_float(u);
}

__device__ inline unsigned short f2bf(float f) {  // RNE float->bf16 bits
  unsigned u = __float_as_uint(f);
  unsigned lsb = (u >> 16) & 1u;
  u += 0x7fffu + lsb;
  return (unsigned short)(u >> 16);
}
__device__ inline float bf2f(unsigned short h) {
  return __uint_as_float(((unsigned)h) << 16);
}

__device__ inline void gload16(const void* gsrc, void* ldst) {
  __builtin_amdgcn_global_load_lds(
      (const __attribute__((address_space(1))) unsigned int*)gsrc,
      (__attribute__((address_space(3))) unsigned int*)ldst, 16, 0, 0);
}

// ---------------- K1: per-row rsqrt(mean(x^2)+eps) ----------------
__global__ void row_rinv_k(const float* __restrict__ X, float* __restrict__ rinv) {
  __shared__ float l4[4];
  int row = blockIdx.x;
  float4 v = ((const float4*)(X + (size_t)row * D_DIM))[threadIdx.x];
  float ss = v.x * v.x + v.y * v.y + v.z * v.z + v.w * v.w;
  for (int o = 32; o > 0; o >>= 1) ss += __shfl_xor(ss, o);
  int lane = threadIdx.x & 63, w = threadIdx.x >> 6;
  if (lane == 0) l4[w] = ss;
  __syncthreads();
  if (threadIdx.x == 0) {
    float t = l4[0] + l4[1] + l4[2] + l4[3];
    rinv[row] = rsqrtf(t * (1.0f / D_DIM) + 1e-6f);
  }
}

// ---------------- K1b: split W[n,k]*cw[k] into bf16 hi/lo ----------------
__global__ void split_w_k(const float* __restrict__ W, const float* __restrict__ cw,
                          unsigned short* __restrict__ H, unsigned short* __restrict__ L) {
  int row = blockIdx.x;
  int c0 = threadIdx.x * 4;
  float4 wv = *(const float4*)(W + (size_t)row * D_DIM + c0);
  float4 cv = *(const float4*)(cw + c0);
  float y[4] = {wv.x * cv.x, wv.y * cv.y, wv.z * cv.z, wv.w * cv.w};
  unsigned short h[4], l[4];
#pragma unroll
  for (int i = 0; i < 4; ++i) {
    h[i] = f2bf(y[i]);
    l[i] = f2bf(y[i] - bf2f(h[i]));
  }
  *(ushort4*)(H + (size_t)row * D_DIM + c0) = make_ushort4(h[0], h[1], h[2], h[3]);
  *(ushort4*)(L + (size_t)row * D_DIM + c0) = make_ushort4(l[0], l[1], l[2], l[3]);
}

// ---------------- K2: O(hi,lo) = rowscale(A_f32) @ B(hi,lo)^T ----------------
// A: [M][1024] f32 (raw, rinv applied in epilogue). B: [128*gy..][1024] bf16 pair.
// 128x128 tile, BK=32, 4 waves (2x2), 16x16x32 MFMA, 3-product split.
__global__ __launch_bounds__(256, 2) void gemm_a32_k(
    const float* __restrict__ A, const float* __restrict__ rinv,
    const unsigned short* __restrict__ BH, const unsigned short* __restrict__ BL,
    unsigned short* __restrict__ OH, unsigned short* __restrict__ OL) {
  __shared__ __align__(16) float lA[128 * 32];        // XOR-swizzled (16B chunks)
  __shared__ __align__(16) unsigned short lBH[128 * 32];
  __shared__ __align__(16) unsigned short lBL[128 * 32];
  __shared__ float ldsR[128];

  int tid = threadIdx.x;
  int lane = tid & 63, wid = tid >> 6;
  int wr = wid >> 1, wc = wid & 1;
  int fr = lane & 15, fg = lane >> 4;
  long m0 = (long)blockIdx.x * 128;
  long n0 = (long)blockIdx.y * 128;

  if (tid < 128) ldsR[tid] = rinv[m0 + tid];

  f32x4 acc[4][4] = {};

  for (int kk = 0; kk < D_DIM; kk += BK) {
    // stage A f32 tile [128][32]: 1024 x 16B chunks; swizzle source so that
    // LDS chunk (r,c) holds global chunk (r, c^(r&7)).
#pragma unroll
    for (int i = 0; i < 4; ++i) {
      int chunk = i * 256 + tid;
      int r = chunk >> 3, c = chunk & 7;
      int cs = c ^ (r & 7);
      const float* src = A + (m0 + r) * (long)D_DIM + kk + cs * 4;
      gload16(src, (void*)(lA + ((i * 256 + (tid & ~63)) << 2)));
    }
    // stage B bf16 tiles [128][32]
#pragma unroll
    for (int i = 0; i < 2; ++i) {
      int chunk = i * 256 + tid;
      int r = chunk >> 2, c = chunk & 3;
      long boff = (n0 + r) * (long)D_DIM + kk + c * 8;
      int lo = (i * 256 + (tid & ~63)) << 3;
      gload16(BH + boff, (void*)(lBH + lo));
      gload16(BL + boff, (void*)(lBL + lo));
    }
    __syncthreads();

    bf16x8 aH[4], aL[4], bH[4], bL[4];
#pragma unroll
    for (int m = 0; m < 4; ++m) {
      int row = wr * 64 + m * 16 + fr;
      int rm = row & 7;
      f32x4 p0 = *(const f32x4*)(lA + row * 32 + (((fg * 2 + 0) ^ rm) * 4));
      f32x4 p1 = *(const f32x4*)(lA + row * 32 + (((fg * 2 + 1) ^ rm) * 4));
#pragma unroll
      for (int e = 0; e < 8; ++e) {
        float f = (e < 4) ? p0[e] : p1[e - 4];
        unsigned short h = f2bf(f);
        aH[m][e] = (short)h;
        aL[m][e] = (short)f2bf(f - bf2f(h));
      }
    }
#pragma unroll
    for (int n = 0; n < 4; ++n) {
      int row = wc * 64 + n * 16 + fr;
      bH[n] = *(const bf16x8*)(lBH + row * 32 + fg * 8);
      bL[n] = *(const bf16x8*)(lBL + row * 32 + fg * 8);
    }
#pragma unroll
    for (int m = 0; m < 4; ++m)
#pragma unroll
      for (int n = 0; n < 4; ++n) {
        acc[m][n] = __builtin_amdgcn_mfma_f32_16x16x32_bf16(aH[m], bH[n], acc[m][n], 0, 0, 0);
        acc[m][n] = __builtin_amdgcn_mfma_f32_16x16x32_bf16(aH[m], bL[n], acc[m][n], 0, 0, 0);
        acc[m][n] = __builtin_amdgcn_mfma_f32_16x16x32_bf16(aL[m], bH[n], acc[m][n], 0, 0, 0);
      }
    __syncthreads();
  }

  // epilogue: scale by rinv[row], split to bf16 hi/lo, store.
  // C/D layout (m89-verified): col = lane&15, row = (lane>>4)*4 + j
#pragma unroll
  for (int m = 0; m < 4; ++m) {
#pragma unroll
    for (int j = 0; j < 4; ++j) {
      int rloc = wr * 64 + m * 16 + fg * 4 + j;
      float rv = ldsR[rloc];
      long grow = m0 + rloc;
#pragma unroll
      for (int n = 0; n < 4; ++n) {
        long gcol = n0 + wc * 64 + n * 16 + fr;
        float v = acc[m][n][j] * rv;
        unsigned short h = f2bf(v);
        OH[grow * D_DIM + gcol] = h;
        OL[grow * D_DIM + gcol] = f2bf(v - bf2f(h));
      }
    }
  }
}

// ---------------- K3: scores tile + column-max reduce -> atomicMax ----------------
__global__ __launch_bounds__(256, 2) void gemm_scores_k(
    const unsigned short* __restrict__ QH, const unsigned short* __restrict__ QL,
    const unsigned short* __restrict__ KH, const unsigned short* __restrict__ KL,
    unsigned* __restrict__ gmax, int b_base) {
  __shared__ __align__(16) unsigned short lAH[128 * 32], lAL[128 * 32];
  __shared__ __align__(16) unsigned short lBH[128 * 32], lBL[128 * 32];

  int tid = threadIdx.x;
  int lane = tid & 63, wid = tid >> 6;
  int wr = wid >> 1, wc = wid & 1;
  int fr = lane & 15, fg = lane >> 4;
  long m0 = (long)blockIdx.x * 128;
  long n0 = (long)blockIdx.y * 128;

  f32x4 acc[4][4] = {};

  for (int kk = 0; kk < D_DIM; kk += BK) {
#pragma unroll
    for (int i = 0; i < 2; ++i) {
      int chunk = i * 256 + tid;
      int r = chunk >> 2, c = chunk & 3;
      long aoff = (m0 + r) * (long)D_DIM + kk + c * 8;
      long boff = (n0 + r) * (long)D_DIM + kk + c * 8;
      int lo = (i * 256 + (tid & ~63)) << 3;
      gload16(QH + aoff, (void*)(lAH + lo));
      gload16(QL + aoff, (void*)(lAL + lo));
      gload16(KH + boff, (void*)(lBH + lo));
      gload16(KL + boff, (void*)(lBL + lo));
    }
    __syncthreads();

    bf16x8 aH[4], aL[4], bH[4], bL[4];
#pragma unroll
    for (int m = 0; m < 4; ++m) {
      int row = wr * 64 + m * 16 + fr;
      aH[m] = *(const bf16x8*)(lAH + row * 32 + fg * 8);
      aL[m] = *(const bf16x8*)(lAL + row * 32 + fg * 8);
    }
#pragma unroll
    for (int n = 0; n < 4; ++n) {
      int row = wc * 64 + n * 16 + fr;
      bH[n] = *(const bf16x8*)(lBH + row * 32 + fg * 8);
      bL[n] = *(const bf16x8*)(lBL + row * 32 + fg * 8);
    }
#pragma unroll
    for (int m = 0; m < 4; ++m)
#pragma unroll
      for (int n = 0; n < 4; ++n) {
        acc[m][n] = __builtin_amdgcn_mfma_f32_16x16x32_bf16(aH[m], bH[n], acc[m][n], 0, 0, 0);
        acc[m][n] = __builtin_amdgcn_mfma_f32_16x16x32_bf16(aH[m], bL[n], acc[m][n], 0, 0, 0);
        acc[m][n] = __builtin_amdgcn_mfma_f32_16x16x32_bf16(aL[m], bH[n], acc[m][n], 0, 0, 0);
      }
    __syncthreads();
  }

  // per-column max over this tile's 128 rows; scale by 2^-5 (exact), encode, atomic.
  int b = b_base + (int)(m0 >> 11);
#pragma unroll
  for (int n = 0; n < 4; ++n) {
    float v = -3.0e38f;
#pragma unroll
    for (int m = 0; m < 4; ++m)
#pragma unroll
      for (int j = 0; j < 4; ++j) v = fmaxf(v, acc[m][n][j]);
    v = fmaxf(v, __shfl_xor(v, 16));
    v = fmaxf(v, __shfl_xor(v, 32));
    if (fg == 0) {
      long col = n0 + wc * 64 + n * 16 + fr;
      atomicMax(&gmax[(long)b * NE + col], encf(v * 0.03125f));
    }
  }
}

// ---------------- K4: per-batch exact top-64 cutoff + softmax weights ----------------
__global__ void topk_weights_k(const unsigned* __restrict__ gmax,
                               const float* __restrict__ alpha_p,
                               float* __restrict__ wout, int* __restrict__ idx,
                               int* __restrict__ cnt) {
  __shared__ unsigned enc[NE];
  __shared__ unsigned ubc[4];
  __shared__ float l4[4];
  __shared__ int ic[257];
  int tid = threadIdx.x;
  int lane = tid & 63, w = tid >> 6;
  const unsigned* g = gmax + (size_t)blockIdx.x * NE;
  for (int i = tid; i < NE; i += 256) enc[i] = g[i];
  __syncthreads();

  // block max (encoded domain, monotonic)
  unsigned mx = 0;
  for (int i = tid; i < NE; i += 256) mx = enc[i] > mx ? enc[i] : mx;
  for (int o = 32; o > 0; o >>= 1) {
    unsigned other = (unsigned)__shfl_xor((int)mx, o);
    if (other > mx) mx = other;
  }
  if (lane == 0) ubc[w] = mx;
  __syncthreads();
  unsigned m1e = ubc[0];
  for (int t = 1; t < 4; ++t) m1e = ubc[t] > m1e ? ubc[t] : m1e;
  float m1 = decf(m1e);

  // binary search: largest u with count(enc >= u) >= KTOP  -> u = enc(64th largest)
  unsigned cur = 0;
  for (int bit = 31; bit >= 0; --bit) {
    unsigned cand = cur | (1u << bit);
    int c = 0;
    for (int i = tid; i < NE; i += 256) c += (enc[i] >= cand) ? 1 : 0;
    for (int o = 32; o > 0; o >>= 1) c += __shfl_xor(c, o);
    __syncthreads();
    if (lane == 0) ic[w] = c;
    __syncthreads();
    int tot = ic[0] + ic[1] + ic[2] + ic[3];
    if (tot >= KTOP) cur = cand;
  }

  // softmax sums
  float sd = 0.f, ssum = 0.f;
  for (int i = tid; i < NE; i += 256) {
    float e = expf(decf(enc[i]) - m1);
    sd += e;
    if (enc[i] >= cur) ssum += e;
  }
  for (int o = 32; o > 0; o >>= 1) { sd += __shfl_xor(sd, o); ssum += __shfl_xor(ssum, o); }
  __syncthreads();
  if (lane == 0) { l4[w] = sd; }
  __syncthreads();
  float SD = l4[0] + l4[1] + l4[2] + l4[3];
  __syncthreads();
  if (lane == 0) { l4[w] = ssum; }
  __syncthreads();
  float SS = l4[0] + l4[1] + l4[2] + l4[3];

  float alpha = alpha_p[0];
  float wd = alpha / SD;
  float ws_ = (1.0f - alpha) / SS;
  for (int i = tid; i < NE; i += 256) {
    float e = expf(decf(enc[i]) - m1);
    float wv = wd * e + ((enc[i] >= cur) ? ws_ * e : 0.0f);
    wout[(size_t)blockIdx.x * NE + i] = wv;
  }

  // deterministic compaction of selected indices (for K5 sparse path)
  int myc = 0;
  for (int i = tid; i < NE; i += 256) myc += (enc[i] >= cur) ? 1 : 0;
  __syncthreads();
  ic[tid] = myc;
  __syncthreads();
  if (tid == 0) {
    int s = 0;
    for (int t = 0; t < 256; ++t) { int v = ic[t]; ic[t] = s; s += v; }
    ic[256] = s;
    cnt[blockIdx.x] = s;
  }
  __syncthreads();
  int off = ic[tid];
  for (int i = tid; i < NE; i += 256)
    if (enc[i] >= cur) idx[(size_t)blockIdx.x * NE + (off++)] = i;
}

// ---------------- K5: O = rmsnorm(weights @ En, on_w) ----------------
__global__ void out_o_k(const float* __restrict__ wts, const float* __restrict__ E,
                        const float* __restrict__ rinvE, const float* __restrict__ sn_w,
                        const float* __restrict__ on_w, const float* __restrict__ alpha_p,
                        const int* __restrict__ idx, const int* __restrict__ cnt,
                        float* __restrict__ O) {
  __shared__ float l4[4];
  int b = blockIdx.x, tid = threadIdx.x;
  float acc[4] = {0.f, 0.f, 0.f, 0.f};
  float alpha = alpha_p[0];
  if (alpha == 0.0f) {
    int nsel = cnt[b];
    for (int j = 0; j < nsel; ++j) {
      int n = idx[(size_t)b * NE + j];
      float wv = wts[(size_t)b * NE + n] * rinvE[n];
      const float* er = E + (size_t)n * D_DIM;
#pragma unroll
      for (int i = 0; i < 4; ++i) acc[i] += wv * er[tid + 256 * i];
    }
  } else {
    for (int n = 0; n < NE; ++n) {
      float wv = wts[(size_t)b * NE + n] * rinvE[n];
      const float* er = E + (size_t)n * D_DIM;
#pragma unroll
      for (int i = 0; i < 4; ++i) acc[i] += wv * er[tid + 256 * i];
    }
  }
  float ssq = 0.f;
#pragma unroll
  for (int i = 0; i < 4; ++i) {
    acc[i] *= sn_w[tid + 256 * i];
    ssq += acc[i] * acc[i];
  }
  for (int o = 32; o > 0; o >>= 1) ssq += __shfl_xor(ssq, o);
  int lane = tid & 63, w = tid >> 6;
  if (lane == 0) l4[w] = ssq;
  __syncthreads();
  float tot = l4[0] + l4[1] + l4[2] + l4[3];
  float r = rsqrtf(tot * (1.0f / D_DIM) + 1e-6f);
#pragma unroll
  for (int i = 0; i < 4; ++i)
    O[(size_t)b * D_DIM + tid + 256 * i] = acc[i] * r * on_w[tid + 256 * i];
}

}  // namespace

extern "C" void kernel_launch(void* const* d_in, const int* in_sizes, int n_in,
                              void* d_out, int out_size, void* d_ws, size_t ws_size,
                              hipStream_t stream) {
  const float* X     = (const float*)d_in[0];
  const float* alpha = (const float*)d_in[1];
  const float* E     = (const float*)d_in[2];
  const float* Wq    = (const float*)d_in[3];
  const float* Wk    = (const float*)d_in[4];
  const float* xn_w  = (const float*)d_in[5];
  const float* sn_w  = (const float*)d_in[6];
  const float* on_w  = (const float*)d_in[7];
  float* O    = (float*)d_out;                       // [16][1024]
  float* Wout = (float*)d_out + (size_t)BATCH * D_DIM;  // [16][4096]

  char* ws = (char*)d_ws;
  size_t off = 0;
  auto alloc = [&](size_t bytes) {
    char* p = ws + off;
    off += (bytes + 255) & ~(size_t)255;
    return p;
  };
  unsigned short* QH  = (unsigned short*)alloc((size_t)MCH * D_DIM * 2);
  unsigned short* QL  = (unsigned short*)alloc((size_t)MCH * D_DIM * 2);
  unsigned short* KmH = (unsigned short*)alloc((size_t)NE * D_DIM * 2);
  unsigned short* KmL = (unsigned short*)alloc((size_t)NE * D_DIM * 2);
  unsigned short* WqH = (unsigned short*)alloc((size_t)D_DIM * D_DIM * 2);
  unsigned short* WqL = (unsigned short*)alloc((size_t)D_DIM * D_DIM * 2);
  unsigned short* WkH = (unsigned short*)alloc((size_t)D_DIM * D_DIM * 2);
  unsigned short* WkL = (unsigned short*)alloc((size_t)D_DIM * D_DIM * 2);
  float* rinvX = (float*)alloc((size_t)MX * 4);
  float* rinvE = (float*)alloc((size_t)NE * 4);
  unsigned* gmax = (unsigned*)alloc((size_t)BATCH * NE * 4);
  int* idx = (int*)alloc((size_t)BATCH * NE * 4);
  int* cnt = (int*)alloc((size_t)BATCH * 4);
  if (off > ws_size) return;  // needs ~60 MB scratch

  row_rinv_k<<<MX, 256, 0, stream>>>(X, rinvX);
  row_rinv_k<<<NE, 256, 0, stream>>>(E, rinvE);
  split_w_k<<<D_DIM, 256, 0, stream>>>(Wq, xn_w, WqH, WqL);
  split_w_k<<<D_DIM, 256, 0, stream>>>(Wk, sn_w, WkH, WkL);

  // Km = (E * rinvE) @ (Wk*sn_w)^T, split output
  gemm_a32_k<<<dim3(NE / 128, D_DIM / 128), 256, 0, stream>>>(E, rinvE, WkH, WkL, KmH, KmL);

  hipMemsetAsync(gmax, 0, (size_t)BATCH * NE * 4, stream);

  for (int ch = 0; ch < MX / MCH; ++ch) {
    long m0 = (long)ch * MCH;
    gemm_a32_k<<<dim3(MCH / 128, D_DIM / 128), 256, 0, stream>>>(
        X + m0 * D_DIM, rinvX + m0, WqH, WqL, QH, QL);
    gemm_scores_k<<<dim3(MCH / 128, NE / 128), 256, 0, stream>>>(
        QH, QL, KmH, KmL, gmax, (int)(m0 >> 11));
  }

  topk_weights_k<<<BATCH, 256, 0, stream>>>(gmax, alpha, Wout, idx, cnt);
  out_o_k<<<BATCH, 256, 0, stream>>>(Wout, E, rinvE, sn_w, on_w, alpha, idx, cnt, O);
}

// Round 2
// 1070.852 us; speedup vs baseline: 1.0100x; 1.0100x over previous
//
#include <hip/hip_runtime.h>

// BasisAttention: B=16,S=2048,D=1024,N=4096,K_TOP=64. fp32 in/out.
// Strategy: fp32-accurate GEMMs via 3-product bf16 split (hi/lo) MFMA.
// R2: XOR chunk-swizzle on bf16 LDS tiles (8-way bank conflict fix;
//     pre-swizzled global source + swizzled read, linear gload_lds dest).

namespace {

constexpr int D_DIM = 1024;
constexpr int NE    = 4096;
constexpr int BATCH = 16;
constexpr int SEQ   = 2048;
constexpr int MX    = BATCH * SEQ;   // 32768
constexpr int MCH   = 8192;          // m-chunk (4 chunks)
constexpr int KTOP  = 64;
constexpr int BK    = 32;

using f32x4  = __attribute__((ext_vector_type(4))) float;
using bf16x8 = __attribute__((ext_vector_type(8))) short;

__device__ inline unsigned encf(float f) {
  unsigned u = __float_as_uint(f);
  return (u & 0x80000000u) ? ~u : (u | 0x80000000u);
}
__device__ inline float decf(unsigned e) {
  unsigned u = (e & 0x80000000u) ? (e ^ 0x80000000u) : ~e;
  return __uint_as_float(u);
}

__device__ inline unsigned short f2bf(float f) {  // RNE float->bf16 bits
  unsigned u = __float_as_uint(f);
  unsigned lsb = (u >> 16) & 1u;
  u += 0x7fffu + lsb;
  return (unsigned short)(u >> 16);
}
__device__ inline float bf2f(unsigned short h) {
  return __uint_as_float(((unsigned)h) << 16);
}

__device__ inline void gload16(const void* gsrc, void* ldst) {
  __builtin_amdgcn_global_load_lds(
      (const __attribute__((address_space(1))) unsigned int*)gsrc,
      (__attribute__((address_space(3))) unsigned int*)ldst, 16, 0, 0);
}

// ---------------- K1: per-row rsqrt(mean(x^2)+eps) ----------------
__global__ void row_rinv_k(const float* __restrict__ X, float* __restrict__ rinv) {
  __shared__ float l4[4];
  int row = blockIdx.x;
  float4 v = ((const float4*)(X + (size_t)row * D_DIM))[threadIdx.x];
  float ss = v.x * v.x + v.y * v.y + v.z * v.z + v.w * v.w;
  for (int o = 32; o > 0; o >>= 1) ss += __shfl_xor(ss, o);
  int lane = threadIdx.x & 63, w = threadIdx.x >> 6;
  if (lane == 0) l4[w] = ss;
  __syncthreads();
  if (threadIdx.x == 0) {
    float t = l4[0] + l4[1] + l4[2] + l4[3];
    rinv[row] = rsqrtf(t * (1.0f / D_DIM) + 1e-6f);
  }
}

// ---------------- K1b: split W[n,k]*cw[k] into bf16 hi/lo ----------------
__global__ void split_w_k(const float* __restrict__ W, const float* __restrict__ cw,
                          unsigned short* __restrict__ H, unsigned short* __restrict__ L) {
  int row = blockIdx.x;
  int c0 = threadIdx.x * 4;
  float4 wv = *(const float4*)(W + (size_t)row * D_DIM + c0);
  float4 cv = *(const float4*)(cw + c0);
  float y[4] = {wv.x * cv.x, wv.y * cv.y, wv.z * cv.z, wv.w * cv.w};
  unsigned short h[4], l[4];
#pragma unroll
  for (int i = 0; i < 4; ++i) {
    h[i] = f2bf(y[i]);
    l[i] = f2bf(y[i] - bf2f(h[i]));
  }
  *(ushort4*)(H + (size_t)row * D_DIM + c0) = make_ushort4(h[0], h[1], h[2], h[3]);
  *(ushort4*)(L + (size_t)row * D_DIM + c0) = make_ushort4(l[0], l[1], l[2], l[3]);
}

// ---------------- K2: O(hi,lo) = rowscale(A_f32) @ B(hi,lo)^T ----------------
// A: [M][1024] f32 (raw, rinv applied in epilogue). B: [128*gy..][1024] bf16 pair.
// 128x128 tile, BK=32, 4 waves (2x2), 16x16x32 MFMA, 3-product split.
__global__ __launch_bounds__(256, 2) void gemm_a32_k(
    const float* __restrict__ A, const float* __restrict__ rinv,
    const unsigned short* __restrict__ BH, const unsigned short* __restrict__ BL,
    unsigned short* __restrict__ OH, unsigned short* __restrict__ OL) {
  __shared__ __align__(16) float lA[128 * 32];        // XOR-swizzled (16B chunks)
  __shared__ __align__(16) unsigned short lBH[128 * 32];
  __shared__ __align__(16) unsigned short lBL[128 * 32];
  __shared__ float ldsR[128];

  int tid = threadIdx.x;
  int lane = tid & 63, wid = tid >> 6;
  int wr = wid >> 1, wc = wid & 1;
  int fr = lane & 15, fg = lane >> 4;
  long m0 = (long)blockIdx.x * 128;
  long n0 = (long)blockIdx.y * 128;

  if (tid < 128) ldsR[tid] = rinv[m0 + tid];

  f32x4 acc[4][4] = {};

  for (int kk = 0; kk < D_DIM; kk += BK) {
    // stage A f32 tile [128][32]: 1024 x 16B chunks; swizzle source so that
    // LDS chunk (r,c) holds global chunk (r, c^(r&7)).
#pragma unroll
    for (int i = 0; i < 4; ++i) {
      int chunk = i * 256 + tid;
      int r = chunk >> 3, c = chunk & 7;
      int cs = c ^ (r & 7);
      const float* src = A + (m0 + r) * (long)D_DIM + kk + cs * 4;
      gload16(src, (void*)(lA + ((i * 256 + (tid & ~63)) << 2)));
    }
    // stage B bf16 tiles [128][32]: 4 chunks/row, swizzled c^((r>>1)&3)
#pragma unroll
    for (int i = 0; i < 2; ++i) {
      int chunk = i * 256 + tid;
      int r = chunk >> 2, c = chunk & 3;
      int cs = c ^ ((r >> 1) & 3);
      long boff = (n0 + r) * (long)D_DIM + kk + cs * 8;
      int lo = (i * 256 + (tid & ~63)) << 3;
      gload16(BH + boff, (void*)(lBH + lo));
      gload16(BL + boff, (void*)(lBL + lo));
    }
    __syncthreads();

    bf16x8 aH[4], aL[4], bH[4], bL[4];
#pragma unroll
    for (int m = 0; m < 4; ++m) {
      int row = wr * 64 + m * 16 + fr;
      int rm = row & 7;
      f32x4 p0 = *(const f32x4*)(lA + row * 32 + (((fg * 2 + 0) ^ rm) * 4));
      f32x4 p1 = *(const f32x4*)(lA + row * 32 + (((fg * 2 + 1) ^ rm) * 4));
#pragma unroll
      for (int e = 0; e < 8; ++e) {
        float f = (e < 4) ? p0[e] : p1[e - 4];
        unsigned short h = f2bf(f);
        aH[m][e] = (short)h;
        aL[m][e] = (short)f2bf(f - bf2f(h));
      }
    }
#pragma unroll
    for (int n = 0; n < 4; ++n) {
      int row = wc * 64 + n * 16 + fr;
      int sc = fg ^ ((row >> 1) & 3);
      bH[n] = *(const bf16x8*)(lBH + row * 32 + sc * 8);
      bL[n] = *(const bf16x8*)(lBL + row * 32 + sc * 8);
    }
#pragma unroll
    for (int m = 0; m < 4; ++m)
#pragma unroll
      for (int n = 0; n < 4; ++n) {
        acc[m][n] = __builtin_amdgcn_mfma_f32_16x16x32_bf16(aH[m], bH[n], acc[m][n], 0, 0, 0);
        acc[m][n] = __builtin_amdgcn_mfma_f32_16x16x32_bf16(aH[m], bL[n], acc[m][n], 0, 0, 0);
        acc[m][n] = __builtin_amdgcn_mfma_f32_16x16x32_bf16(aL[m], bH[n], acc[m][n], 0, 0, 0);
      }
    __syncthreads();
  }

  // epilogue: scale by rinv[row], split to bf16 hi/lo, store.
  // C/D layout (m89-verified): col = lane&15, row = (lane>>4)*4 + j
#pragma unroll
  for (int m = 0; m < 4; ++m) {
#pragma unroll
    for (int j = 0; j < 4; ++j) {
      int rloc = wr * 64 + m * 16 + fg * 4 + j;
      float rv = ldsR[rloc];
      long grow = m0 + rloc;
#pragma unroll
      for (int n = 0; n < 4; ++n) {
        long gcol = n0 + wc * 64 + n * 16 + fr;
        float v = acc[m][n][j] * rv;
        unsigned short h = f2bf(v);
        OH[grow * D_DIM + gcol] = h;
        OL[grow * D_DIM + gcol] = f2bf(v - bf2f(h));
      }
    }
  }
}

// ---------------- K3: scores tile + column-max reduce -> atomicMax ----------------
__global__ __launch_bounds__(256, 2) void gemm_scores_k(
    const unsigned short* __restrict__ QH, const unsigned short* __restrict__ QL,
    const unsigned short* __restrict__ KH, const unsigned short* __restrict__ KL,
    unsigned* __restrict__ gmax, int b_base) {
  __shared__ __align__(16) unsigned short lAH[128 * 32], lAL[128 * 32];
  __shared__ __align__(16) unsigned short lBH[128 * 32], lBL[128 * 32];

  int tid = threadIdx.x;
  int lane = tid & 63, wid = tid >> 6;
  int wr = wid >> 1, wc = wid & 1;
  int fr = lane & 15, fg = lane >> 4;
  long m0 = (long)blockIdx.x * 128;
  long n0 = (long)blockIdx.y * 128;

  f32x4 acc[4][4] = {};

  for (int kk = 0; kk < D_DIM; kk += BK) {
    // stage 4 bf16 tiles [128][32]: swizzled source chunk c^((r>>1)&3)
#pragma unroll
    for (int i = 0; i < 2; ++i) {
      int chunk = i * 256 + tid;
      int r = chunk >> 2, c = chunk & 3;
      int cs = c ^ ((r >> 1) & 3);
      long aoff = (m0 + r) * (long)D_DIM + kk + cs * 8;
      long boff = (n0 + r) * (long)D_DIM + kk + cs * 8;
      int lo = (i * 256 + (tid & ~63)) << 3;
      gload16(QH + aoff, (void*)(lAH + lo));
      gload16(QL + aoff, (void*)(lAL + lo));
      gload16(KH + boff, (void*)(lBH + lo));
      gload16(KL + boff, (void*)(lBL + lo));
    }
    __syncthreads();

    bf16x8 aH[4], aL[4], bH[4], bL[4];
#pragma unroll
    for (int m = 0; m < 4; ++m) {
      int row = wr * 64 + m * 16 + fr;
      int sc = fg ^ ((row >> 1) & 3);
      aH[m] = *(const bf16x8*)(lAH + row * 32 + sc * 8);
      aL[m] = *(const bf16x8*)(lAL + row * 32 + sc * 8);
    }
#pragma unroll
    for (int n = 0; n < 4; ++n) {
      int row = wc * 64 + n * 16 + fr;
      int sc = fg ^ ((row >> 1) & 3);
      bH[n] = *(const bf16x8*)(lBH + row * 32 + sc * 8);
      bL[n] = *(const bf16x8*)(lBL + row * 32 + sc * 8);
    }
#pragma unroll
    for (int m = 0; m < 4; ++m)
#pragma unroll
      for (int n = 0; n < 4; ++n) {
        acc[m][n] = __builtin_amdgcn_mfma_f32_16x16x32_bf16(aH[m], bH[n], acc[m][n], 0, 0, 0);
        acc[m][n] = __builtin_amdgcn_mfma_f32_16x16x32_bf16(aH[m], bL[n], acc[m][n], 0, 0, 0);
        acc[m][n] = __builtin_amdgcn_mfma_f32_16x16x32_bf16(aL[m], bH[n], acc[m][n], 0, 0, 0);
      }
    __syncthreads();
  }

  // per-column max over this tile's 128 rows; scale by 2^-5 (exact), encode, atomic.
  int b = b_base + (int)(m0 >> 11);
#pragma unroll
  for (int n = 0; n < 4; ++n) {
    float v = -3.0e38f;
#pragma unroll
    for (int m = 0; m < 4; ++m)
#pragma unroll
      for (int j = 0; j < 4; ++j) v = fmaxf(v, acc[m][n][j]);
    v = fmaxf(v, __shfl_xor(v, 16));
    v = fmaxf(v, __shfl_xor(v, 32));
    if (fg == 0) {
      long col = n0 + wc * 64 + n * 16 + fr;
      atomicMax(&gmax[(long)b * NE + col], encf(v * 0.03125f));
    }
  }
}

// ---------------- K4: per-batch exact top-64 cutoff + softmax weights ----------------
__global__ void topk_weights_k(const unsigned* __restrict__ gmax,
                               const float* __restrict__ alpha_p,
                               float* __restrict__ wout, int* __restrict__ idx,
                               int* __restrict__ cnt) {
  __shared__ unsigned enc[NE];
  __shared__ unsigned ubc[4];
  __shared__ float l4[4];
  __shared__ int ic[257];
  int tid = threadIdx.x;
  int lane = tid & 63, w = tid >> 6;
  const unsigned* g = gmax + (size_t)blockIdx.x * NE;
  for (int i = tid; i < NE; i += 256) enc[i] = g[i];
  __syncthreads();

  // block max (encoded domain, monotonic)
  unsigned mx = 0;
  for (int i = tid; i < NE; i += 256) mx = enc[i] > mx ? enc[i] : mx;
  for (int o = 32; o > 0; o >>= 1) {
    unsigned other = (unsigned)__shfl_xor((int)mx, o);
    if (other > mx) mx = other;
  }
  if (lane == 0) ubc[w] = mx;
  __syncthreads();
  unsigned m1e = ubc[0];
  for (int t = 1; t < 4; ++t) m1e = ubc[t] > m1e ? ubc[t] : m1e;
  float m1 = decf(m1e);

  // binary search: largest u with count(enc >= u) >= KTOP  -> u = enc(64th largest)
  unsigned cur = 0;
  for (int bit = 31; bit >= 0; --bit) {
    unsigned cand = cur | (1u << bit);
    int c = 0;
    for (int i = tid; i < NE; i += 256) c += (enc[i] >= cand) ? 1 : 0;
    for (int o = 32; o > 0; o >>= 1) c += __shfl_xor(c, o);
    __syncthreads();
    if (lane == 0) ic[w] = c;
    __syncthreads();
    int tot = ic[0] + ic[1] + ic[2] + ic[3];
    if (tot >= KTOP) cur = cand;
  }

  // softmax sums
  float sd = 0.f, ssum = 0.f;
  for (int i = tid; i < NE; i += 256) {
    float e = expf(decf(enc[i]) - m1);
    sd += e;
    if (enc[i] >= cur) ssum += e;
  }
  for (int o = 32; o > 0; o >>= 1) { sd += __shfl_xor(sd, o); ssum += __shfl_xor(ssum, o); }
  __syncthreads();
  if (lane == 0) { l4[w] = sd; }
  __syncthreads();
  float SD = l4[0] + l4[1] + l4[2] + l4[3];
  __syncthreads();
  if (lane == 0) { l4[w] = ssum; }
  __syncthreads();
  float SS = l4[0] + l4[1] + l4[2] + l4[3];

  float alpha = alpha_p[0];
  float wd = alpha / SD;
  float ws_ = (1.0f - alpha) / SS;
  for (int i = tid; i < NE; i += 256) {
    float e = expf(decf(enc[i]) - m1);
    float wv = wd * e + ((enc[i] >= cur) ? ws_ * e : 0.0f);
    wout[(size_t)blockIdx.x * NE + i] = wv;
  }

  // deterministic compaction of selected indices (for K5 sparse path)
  int myc = 0;
  for (int i = tid; i < NE; i += 256) myc += (enc[i] >= cur) ? 1 : 0;
  __syncthreads();
  ic[tid] = myc;
  __syncthreads();
  if (tid == 0) {
    int s = 0;
    for (int t = 0; t < 256; ++t) { int v = ic[t]; ic[t] = s; s += v; }
    ic[256] = s;
    cnt[blockIdx.x] = s;
  }
  __syncthreads();
  int off = ic[tid];
  for (int i = tid; i < NE; i += 256)
    if (enc[i] >= cur) idx[(size_t)blockIdx.x * NE + (off++)] = i;
}

// ---------------- K5: O = rmsnorm(weights @ En, on_w) ----------------
__global__ void out_o_k(const float* __restrict__ wts, const float* __restrict__ E,
                        const float* __restrict__ rinvE, const float* __restrict__ sn_w,
                        const float* __restrict__ on_w, const float* __restrict__ alpha_p,
                        const int* __restrict__ idx, const int* __restrict__ cnt,
                        float* __restrict__ O) {
  __shared__ float l4[4];
  int b = blockIdx.x, tid = threadIdx.x;
  float acc[4] = {0.f, 0.f, 0.f, 0.f};
  float alpha = alpha_p[0];
  if (alpha == 0.0f) {
    int nsel = cnt[b];
    for (int j = 0; j < nsel; ++j) {
      int n = idx[(size_t)b * NE + j];
      float wv = wts[(size_t)b * NE + n] * rinvE[n];
      const float* er = E + (size_t)n * D_DIM;
#pragma unroll
      for (int i = 0; i < 4; ++i) acc[i] += wv * er[tid + 256 * i];
    }
  } else {
    for (int n = 0; n < NE; ++n) {
      float wv = wts[(size_t)b * NE + n] * rinvE[n];
      const float* er = E + (size_t)n * D_DIM;
#pragma unroll
      for (int i = 0; i < 4; ++i) acc[i] += wv * er[tid + 256 * i];
    }
  }
  float ssq = 0.f;
#pragma unroll
  for (int i = 0; i < 4; ++i) {
    acc[i] *= sn_w[tid + 256 * i];
    ssq += acc[i] * acc[i];
  }
  for (int o = 32; o > 0; o >>= 1) ssq += __shfl_xor(ssq, o);
  int lane = tid & 63, w = tid >> 6;
  if (lane == 0) l4[w] = ssq;
  __syncthreads();
  float tot = l4[0] + l4[1] + l4[2] + l4[3];
  float r = rsqrtf(tot * (1.0f / D_DIM) + 1e-6f);
#pragma unroll
  for (int i = 0; i < 4; ++i)
    O[(size_t)b * D_DIM + tid + 256 * i] = acc[i] * r * on_w[tid + 256 * i];
}

}  // namespace

extern "C" void kernel_launch(void* const* d_in, const int* in_sizes, int n_in,
                              void* d_out, int out_size, void* d_ws, size_t ws_size,
                              hipStream_t stream) {
  const float* X     = (const float*)d_in[0];
  const float* alpha = (const float*)d_in[1];
  const float* E     = (const float*)d_in[2];
  const float* Wq    = (const float*)d_in[3];
  const float* Wk    = (const float*)d_in[4];
  const float* xn_w  = (const float*)d_in[5];
  const float* sn_w  = (const float*)d_in[6];
  const float* on_w  = (const float*)d_in[7];
  float* O    = (float*)d_out;                       // [16][1024]
  float* Wout = (float*)d_out + (size_t)BATCH * D_DIM;  // [16][4096]

  char* ws = (char*)d_ws;
  size_t off = 0;
  auto alloc = [&](size_t bytes) {
    char* p = ws + off;
    off += (bytes + 255) & ~(size_t)255;
    return p;
  };
  unsigned short* QH  = (unsigned short*)alloc((size_t)MCH * D_DIM * 2);
  unsigned short* QL  = (unsigned short*)alloc((size_t)MCH * D_DIM * 2);
  unsigned short* KmH = (unsigned short*)alloc((size_t)NE * D_DIM * 2);
  unsigned short* KmL = (unsigned short*)alloc((size_t)NE * D_DIM * 2);
  unsigned short* WqH = (unsigned short*)alloc((size_t)D_DIM * D_DIM * 2);
  unsigned short* WqL = (unsigned short*)alloc((size_t)D_DIM * D_DIM * 2);
  unsigned short* WkH = (unsigned short*)alloc((size_t)D_DIM * D_DIM * 2);
  unsigned short* WkL = (unsigned short*)alloc((size_t)D_DIM * D_DIM * 2);
  float* rinvX = (float*)alloc((size_t)MX * 4);
  float* rinvE = (float*)alloc((size_t)NE * 4);
  unsigned* gmax = (unsigned*)alloc((size_t)BATCH * NE * 4);
  int* idx = (int*)alloc((size_t)BATCH * NE * 4);
  int* cnt = (int*)alloc((size_t)BATCH * 4);
  if (off > ws_size) return;  // needs ~60 MB scratch

  row_rinv_k<<<MX, 256, 0, stream>>>(X, rinvX);
  row_rinv_k<<<NE, 256, 0, stream>>>(E, rinvE);
  split_w_k<<<D_DIM, 256, 0, stream>>>(Wq, xn_w, WqH, WqL);
  split_w_k<<<D_DIM, 256, 0, stream>>>(Wk, sn_w, WkH, WkL);

  // Km = (E * rinvE) @ (Wk*sn_w)^T, split output
  gemm_a32_k<<<dim3(NE / 128, D_DIM / 128), 256, 0, stream>>>(E, rinvE, WkH, WkL, KmH, KmL);

  hipMemsetAsync(gmax, 0, (size_t)BATCH * NE * 4, stream);

  for (int ch = 0; ch < MX / MCH; ++ch) {
    long m0 = (long)ch * MCH;
    gemm_a32_k<<<dim3(MCH / 128, D_DIM / 128), 256, 0, stream>>>(
        X + m0 * D_DIM, rinvX + m0, WqH, WqL, QH, QL);
    gemm_scores_k<<<dim3(MCH / 128, NE / 128), 256, 0, stream>>>(
        QH, QL, KmH, KmL, gmax, (int)(m0 >> 11));
  }

  topk_weights_k<<<BATCH, 256, 0, stream>>>(gmax, alpha, Wout, idx, cnt);
  out_o_k<<<BATCH, 256, 0, stream>>>(Wout, E, rinvE, sn_w, on_w, alpha, idx, cnt, O);
}